// Round 12
// baseline (133.666 us; speedup 1.0000x reference)
//
#include <hip/hip_runtime.h>

#define THREADS 256
#define EPT 8                      // elements per thread; chunk = 2048
#define FILL_BLOCKS 4096

// ---------------------------------------------------------------------------
// Block helpers (each leaves sdata reusable: trailing __syncthreads()).
// ---------------------------------------------------------------------------
__device__ __forceinline__ int blockReduceSum(int v, int* sdata) {
    int tid = threadIdx.x;
    sdata[tid] = v;
    __syncthreads();
    for (int off = THREADS >> 1; off > 0; off >>= 1) {
        if (tid < off) sdata[tid] += sdata[tid + off];
        __syncthreads();
    }
    int r = sdata[0];
    __syncthreads();
    return r;
}

__device__ __forceinline__ int blockScanIncl(int v, int* sdata) {
    int tid = threadIdx.x;
    sdata[tid] = v;
    __syncthreads();
    for (int off = 1; off < THREADS; off <<= 1) {
        int t = 0;
        if (tid >= off) t = sdata[tid - off];
        __syncthreads();
        if (tid >= off) sdata[tid] += t;
        __syncthreads();
    }
    int r = sdata[tid];
    __syncthreads();
    return r;
}

// exclusive max-scan (identity -1): result for tid = max over threads < tid
__device__ __forceinline__ int blockExclScanMax(int v, int* sdata) {
    int tid = threadIdx.x;
    sdata[tid] = v;
    __syncthreads();
    for (int off = 1; off < THREADS; off <<= 1) {
        int t = -1;
        if (tid >= off) t = sdata[tid - off];
        __syncthreads();
        if (tid >= off) sdata[tid] = max(sdata[tid], t);
        __syncthreads();
    }
    int r = (tid == 0) ? -1 : sdata[tid - 1];
    __syncthreads();
    return r;
}

// ---------------------------------------------------------------------------
// Find the last segment-start position <= B0-1 (requires B0 > 0).
// ---------------------------------------------------------------------------
__device__ int findPrevStart(const int* __restrict__ idx, int B0,
                             int* sdata, int* s_found) {
    int tid = threadIdx.x;
    if (tid == 0) *s_found = -1;
    __syncthreads();
    int res = -1;
    for (int step = 0; res < 0; ++step) {
        int p = B0 - 1 - step * THREADS - tid;
        int cand = -1;
        if (p >= 0) {
            bool f = (p == 0) || (idx[p - 1] != idx[p]);
            if (f) cand = p;
        }
        sdata[tid] = cand;
        __syncthreads();
        for (int off = THREADS >> 1; off > 0; off >>= 1) {
            if (tid < off) sdata[tid] = max(sdata[tid], sdata[tid + off]);
            __syncthreads();
        }
        if (tid == 0 && sdata[0] >= 0) *s_found = sdata[0];
        __syncthreads();
        res = *s_found;
        __syncthreads();
    }
    return res;
}

// ---------------------------------------------------------------------------
// Kernel A: per-chunk (startCount, sum of local ranks q(p) = p - lastStart).
// ---------------------------------------------------------------------------
__global__ void k_chunkstats(const int* __restrict__ idx, int n,
                             int* __restrict__ chunkCnt,
                             int* __restrict__ chunkTriSum) {
    __shared__ int sdata[THREADS];
    __shared__ int s_tmp;
    int tid = threadIdx.x, bid = blockIdx.x;
    int B0 = bid * (THREADS * EPT);

    int prevStart = 0;
    if (bid > 0) prevStart = findPrevStart(idx, B0, sdata, &s_tmp);

    int base = B0 + tid * EPT;
    int cnt = 0, myLast = -1;
    for (int j = 0; j < EPT; ++j) {
        int p = base + j;
        if (p < n) {
            bool f = (p == 0) || (idx[p - 1] != idx[p]);
            if (f) { ++cnt; myLast = p; }
        }
    }
    int before = blockExclScanMax(myLast, sdata);
    int lastStart = max(prevStart, before);
    int sumq = 0;
    for (int j = 0; j < EPT; ++j) {
        int p = base + j;
        if (p < n) {
            if ((p == 0) || (idx[p - 1] != idx[p])) lastStart = p;
            sumq += p - lastStart;
        }
    }
    int c = blockReduceSum(cnt, sdata);
    int q = blockReduceSum(sumq, sdata);
    if (tid == 0) { chunkCnt[bid] = c; chunkTriSum[bid] = q; }
}

// ---------------------------------------------------------------------------
// Kernel B: chunk-level redundant prefix, emit segOff + triOff + nseg.
// ---------------------------------------------------------------------------
__global__ void k_emit(const int* __restrict__ idx, int n, int NB,
                       const int* __restrict__ chunkCnt,
                       const int* __restrict__ chunkTriSum,
                       int* __restrict__ segOff, int* __restrict__ triOff,
                       int* __restrict__ nsegPtr) {
    __shared__ int sdata[THREADS];
    __shared__ int s_tmp;
    int tid = threadIdx.x, bid = blockIdx.x;
    int B0 = bid * (THREADS * EPT);

    int prevStart = 0;
    if (bid > 0) prevStart = findPrevStart(idx, B0, sdata, &s_tmp);

    int pv = 0, tv = 0;
    for (int i = tid; i < bid; i += THREADS) {
        pv += chunkCnt[i];
        tv += chunkTriSum[i];
    }
    int segBase = blockReduceSum(pv, sdata);
    int triBase = blockReduceSum(tv, sdata);

    int base = B0 + tid * EPT;
    int cnt = 0, myLast = -1;
    for (int j = 0; j < EPT; ++j) {
        int p = base + j;
        if (p < n) {
            bool f = (p == 0) || (idx[p - 1] != idx[p]);
            if (f) { ++cnt; myLast = p; }
        }
    }
    int before = blockExclScanMax(myLast, sdata);
    int lastStart0 = max(prevStart, before);

    int lastStart = lastStart0;
    int sumq = 0;
    for (int j = 0; j < EPT; ++j) {
        int p = base + j;
        if (p < n) {
            if ((p == 0) || (idx[p - 1] != idx[p])) lastStart = p;
            sumq += p - lastStart;
        }
    }

    int inclC = blockScanIncl(cnt, sdata);
    int inclQ = blockScanIncl(sumq, sdata);
    int ord  = segBase + inclC - cnt;
    int tcur = triBase + inclQ - sumq;

    lastStart = lastStart0;
    for (int j = 0; j < EPT; ++j) {
        int p = base + j;
        if (p < n) {
            bool f = (p == 0) || (idx[p - 1] != idx[p]);
            if (f) {
                segOff[ord] = p;
                triOff[ord] = tcur;
                ++ord;
                lastStart = p;
            }
            tcur += p - lastStart;
        }
    }
    if (bid == NB - 1 && tid == THREADS - 1) {
        int nseg = segBase + inclC;
        *nsegPtr = nseg;
        segOff[nseg] = n;                  // sentinel
    }
}

// ---------------------------------------------------------------------------
// Fill helpers.
// ---------------------------------------------------------------------------
// exact decode of backward rank rr for segment size c -> local (a,b), b>a
__device__ __forceinline__ void decodeRank(int rr, int c, int& a, int& b) {
    int k = (int)floorf((sqrtf((float)(8 * rr + 1)) - 1.0f) * 0.5f);
    if (k < 0) k = 0;
    while ((k + 1) * (k + 2) / 2 <= rr) ++k;   // exact fix-up
    while (k * (k + 1) / 2 > rr) --k;
    a = c - 2 - k;
    b = c - 1 - (rr - k * (k + 1) / 2);
}

// nontemporal (streaming, no L2 allocate) stores
typedef int v4i __attribute__((ext_vector_type(4)));
typedef int v2i __attribute__((ext_vector_type(2)));

__device__ __forceinline__ void ntStore1(int* p, int v) {
    __builtin_nontemporal_store(v, p);
}
__device__ __forceinline__ void ntStore2(int* p, int x, int y) {
    v2i v = {x, y};
    __builtin_nontemporal_store(v, (v2i*)p);
}
__device__ __forceinline__ void ntStore4(int* p, int4 v) {
    v4i w = {v.x, v.y, v.z, v.w};
    __builtin_nontemporal_store(w, (v4i*)p);
}

__device__ __forceinline__ void emitOne(int r, int M, int c, int t0, int baseP,
                                        int s, int* __restrict__ outI,
                                        int* __restrict__ outJ,
                                        int* __restrict__ outK) {
    int a, b;
    decodeRank(M - 1 - r, c, a, b);
    int t = t0 + r;
    ntStore1(outI + t, s);
    ntStore1(outJ + t, baseP + a);
    ntStore1(outK + t, baseP + b);
}

// store 4 consecutive ints at element offset t (t % 4 == 0) into stream P
// whose base has element phase PH (= stream_offset % 4) relative to 16B.
template <int PH>
__device__ __forceinline__ void storeQuad(int* __restrict__ P, int t, int4 v) {
    if constexpr (PH == 0) {
        ntStore4(P + t, v);
    } else if constexpr (PH == 2) {
        ntStore2(P + t, v.x, v.y);
        ntStore2(P + t + 2, v.z, v.w);
    } else {
        ntStore1(P + t, v.x);
        ntStore2(P + t + 1, v.y, v.z);
        ntStore1(P + t + 3, v.w);
    }
}

// ---------------------------------------------------------------------------
// Kernel C (hot): triple-balanced fill, QUAD inner loop (r9 structure),
// with NONTEMPORAL output stores. Each lane decodes one rank exactly,
// derives the next 3 via the lexicographic successor rule, stores 16B.
// ---------------------------------------------------------------------------
template <int TMOD4>
__global__ void k_fill(const int* __restrict__ segOff,
                       const int* __restrict__ triOff,
                       const int* __restrict__ nsegPtr, int T,
                       int* __restrict__ outI, int* __restrict__ outJ,
                       int* __restrict__ outK) {
    constexpr int PHJ = TMOD4 & 3;          // element phase of outJ = T % 4
    constexpr int PHK = (2 * TMOD4) & 3;    // element phase of outK = 2T % 4
    int nseg = *nsegPtr;
    int w = blockIdx.x * (THREADS / 64) + (threadIdx.x >> 6);
    int lane = threadIdx.x & 63;
    int nW = gridDim.x * (THREADS / 64);
    long long tlo = (long long)T * w / nW;
    long long thi = (long long)T * (w + 1) / nW;
    if (tlo >= thi) return;

    // largest s with triOff[s] <= tlo
    int lo = 0, hi = nseg - 1;
    while (lo < hi) {
        int mid = (lo + hi + 1) >> 1;
        if (triOff[mid] <= (int)tlo) lo = mid; else hi = mid - 1;
    }
    int s = lo;
    long long t = tlo;
    while (t < thi && s < nseg) {
        int baseP = segOff[s];
        int c = segOff[s + 1] - baseP;
        int M = c * (c - 1) / 2;
        int t0 = triOff[s];
        int rstart = (int)(t - t0);
        int rend = M;
        { long long cap = thi - t0; if (cap < (long long)rend) rend = (int)cap; }

        // quad grid anchored at absolute t % 4 == 0 (t = t0 + r)
        int rA = rstart + ((4 - ((t0 + rstart) & 3)) & 3);
        if (rA > rend) rA = rend;
        int rB = rA + ((rend - rA) & ~3);

        // head (<=3) and tail (<=3) scalars, lane-strided
        for (int r = rstart + lane; r < rA; r += 64)
            emitOne(r, M, c, t0, baseP, s, outI, outJ, outK);
        for (int r = rB + lane; r < rend; r += 64)
            emitOne(r, M, c, t0, baseP, s, outI, outJ, outK);

        // quad interior
        int nq = (rB - rA) >> 2;
        for (int q = lane; q < nq; q += 64) {
            int r = rA + 4 * q;
            int a0, b0;
            decodeRank(M - 1 - r, c, a0, b0);
            int a1 = (b0 == c - 1) ? a0 + 1 : a0;
            int b1 = (b0 == c - 1) ? a0 + 2 : b0 + 1;
            int a2 = (b1 == c - 1) ? a1 + 1 : a1;
            int b2 = (b1 == c - 1) ? a1 + 2 : b1 + 1;
            int a3 = (b2 == c - 1) ? a2 + 1 : a2;
            int b3 = (b2 == c - 1) ? a2 + 2 : b2 + 1;
            int tt = t0 + r;                      // tt % 4 == 0
            storeQuad<0>(outI, tt, make_int4(s, s, s, s));
            storeQuad<PHJ>(outJ, tt,
                make_int4(baseP + a0, baseP + a1, baseP + a2, baseP + a3));
            storeQuad<PHK>(outK, tt,
                make_int4(baseP + b0, baseP + b1, baseP + b2, baseP + b3));
        }
        t = (long long)t0 + rend;
        ++s;
    }
}

extern "C" void kernel_launch(void* const* d_in, const int* in_sizes, int n_in,
                              void* d_out, int out_size, void* d_ws, size_t ws_size,
                              hipStream_t stream) {
    const int* idx = (const int*)d_in[0];
    int n = in_sizes[0];
    int T = out_size / 3;
    int* out = (int*)d_out;
    int* ws = (int*)d_ws;

    // workspace layout (ints)
    int* nsegPtr     = ws;                       // [1]
    int* chunkCnt    = ws + 16;                  // [8192]
    int* chunkTriSum = ws + 16 + 8192;           // [8192]
    int* segOff      = ws + 16 + 16384;          // [n+1] (sentinel at nseg)
    int* triOff      = segOff + (n + 1);         // [n]

    int chunk = THREADS * EPT;                   // 2048
    int NB = (n + chunk - 1) / chunk;            // 782 for n=1.6M

    hipLaunchKernelGGL(k_chunkstats, dim3(NB), dim3(THREADS), 0, stream,
                       idx, n, chunkCnt, chunkTriSum);
    hipLaunchKernelGGL(k_emit, dim3(NB), dim3(THREADS), 0, stream,
                       idx, n, NB, chunkCnt, chunkTriSum,
                       segOff, triOff, nsegPtr);
    int* outI = out;
    int* outJ = out + T;
    int* outK = out + 2 * T;
    switch (T & 3) {
        case 0:
            hipLaunchKernelGGL((k_fill<0>), dim3(FILL_BLOCKS), dim3(THREADS), 0,
                               stream, segOff, triOff, nsegPtr, T, outI, outJ, outK);
            break;
        case 1:
            hipLaunchKernelGGL((k_fill<1>), dim3(FILL_BLOCKS), dim3(THREADS), 0,
                               stream, segOff, triOff, nsegPtr, T, outI, outJ, outK);
            break;
        case 2:
            hipLaunchKernelGGL((k_fill<2>), dim3(FILL_BLOCKS), dim3(THREADS), 0,
                               stream, segOff, triOff, nsegPtr, T, outI, outJ, outK);
            break;
        default:
            hipLaunchKernelGGL((k_fill<3>), dim3(FILL_BLOCKS), dim3(THREADS), 0,
                               stream, segOff, triOff, nsegPtr, T, outI, outJ, outK);
            break;
    }
}

// Round 13
// 86.204 us; speedup vs baseline: 1.5506x; 1.5506x over previous
//
#include <hip/hip_runtime.h>

#define THREADS 256
#define EPT 8                      // elements per thread; chunk = 2048
#define FILL_BLOCKS 1024           // r13: 4096 -> 1024 (shrink concurrent write footprint)

// ---------------------------------------------------------------------------
// Block helpers (each leaves sdata reusable: trailing __syncthreads()).
// ---------------------------------------------------------------------------
__device__ __forceinline__ int blockReduceSum(int v, int* sdata) {
    int tid = threadIdx.x;
    sdata[tid] = v;
    __syncthreads();
    for (int off = THREADS >> 1; off > 0; off >>= 1) {
        if (tid < off) sdata[tid] += sdata[tid + off];
        __syncthreads();
    }
    int r = sdata[0];
    __syncthreads();
    return r;
}

__device__ __forceinline__ int blockScanIncl(int v, int* sdata) {
    int tid = threadIdx.x;
    sdata[tid] = v;
    __syncthreads();
    for (int off = 1; off < THREADS; off <<= 1) {
        int t = 0;
        if (tid >= off) t = sdata[tid - off];
        __syncthreads();
        if (tid >= off) sdata[tid] += t;
        __syncthreads();
    }
    int r = sdata[tid];
    __syncthreads();
    return r;
}

// exclusive max-scan (identity -1): result for tid = max over threads < tid
__device__ __forceinline__ int blockExclScanMax(int v, int* sdata) {
    int tid = threadIdx.x;
    sdata[tid] = v;
    __syncthreads();
    for (int off = 1; off < THREADS; off <<= 1) {
        int t = -1;
        if (tid >= off) t = sdata[tid - off];
        __syncthreads();
        if (tid >= off) sdata[tid] = max(sdata[tid], t);
        __syncthreads();
    }
    int r = (tid == 0) ? -1 : sdata[tid - 1];
    __syncthreads();
    return r;
}

// ---------------------------------------------------------------------------
// Find the last segment-start position <= B0-1 (requires B0 > 0).
// ---------------------------------------------------------------------------
__device__ int findPrevStart(const int* __restrict__ idx, int B0,
                             int* sdata, int* s_found) {
    int tid = threadIdx.x;
    if (tid == 0) *s_found = -1;
    __syncthreads();
    int res = -1;
    for (int step = 0; res < 0; ++step) {
        int p = B0 - 1 - step * THREADS - tid;
        int cand = -1;
        if (p >= 0) {
            bool f = (p == 0) || (idx[p - 1] != idx[p]);
            if (f) cand = p;
        }
        sdata[tid] = cand;
        __syncthreads();
        for (int off = THREADS >> 1; off > 0; off >>= 1) {
            if (tid < off) sdata[tid] = max(sdata[tid], sdata[tid + off]);
            __syncthreads();
        }
        if (tid == 0 && sdata[0] >= 0) *s_found = sdata[0];
        __syncthreads();
        res = *s_found;
        __syncthreads();
    }
    return res;
}

// ---------------------------------------------------------------------------
// Kernel A: per-chunk (startCount, sum of local ranks q(p) = p - lastStart).
// ---------------------------------------------------------------------------
__global__ void k_chunkstats(const int* __restrict__ idx, int n,
                             int* __restrict__ chunkCnt,
                             int* __restrict__ chunkTriSum) {
    __shared__ int sdata[THREADS];
    __shared__ int s_tmp;
    int tid = threadIdx.x, bid = blockIdx.x;
    int B0 = bid * (THREADS * EPT);

    int prevStart = 0;
    if (bid > 0) prevStart = findPrevStart(idx, B0, sdata, &s_tmp);

    int base = B0 + tid * EPT;
    int cnt = 0, myLast = -1;
    for (int j = 0; j < EPT; ++j) {
        int p = base + j;
        if (p < n) {
            bool f = (p == 0) || (idx[p - 1] != idx[p]);
            if (f) { ++cnt; myLast = p; }
        }
    }
    int before = blockExclScanMax(myLast, sdata);
    int lastStart = max(prevStart, before);
    int sumq = 0;
    for (int j = 0; j < EPT; ++j) {
        int p = base + j;
        if (p < n) {
            if ((p == 0) || (idx[p - 1] != idx[p])) lastStart = p;
            sumq += p - lastStart;
        }
    }
    int c = blockReduceSum(cnt, sdata);
    int q = blockReduceSum(sumq, sdata);
    if (tid == 0) { chunkCnt[bid] = c; chunkTriSum[bid] = q; }
}

// ---------------------------------------------------------------------------
// Kernel B: chunk-level redundant prefix, emit segOff + triOff + nseg.
// ---------------------------------------------------------------------------
__global__ void k_emit(const int* __restrict__ idx, int n, int NB,
                       const int* __restrict__ chunkCnt,
                       const int* __restrict__ chunkTriSum,
                       int* __restrict__ segOff, int* __restrict__ triOff,
                       int* __restrict__ nsegPtr) {
    __shared__ int sdata[THREADS];
    __shared__ int s_tmp;
    int tid = threadIdx.x, bid = blockIdx.x;
    int B0 = bid * (THREADS * EPT);

    int prevStart = 0;
    if (bid > 0) prevStart = findPrevStart(idx, B0, sdata, &s_tmp);

    int pv = 0, tv = 0;
    for (int i = tid; i < bid; i += THREADS) {
        pv += chunkCnt[i];
        tv += chunkTriSum[i];
    }
    int segBase = blockReduceSum(pv, sdata);
    int triBase = blockReduceSum(tv, sdata);

    int base = B0 + tid * EPT;
    int cnt = 0, myLast = -1;
    for (int j = 0; j < EPT; ++j) {
        int p = base + j;
        if (p < n) {
            bool f = (p == 0) || (idx[p - 1] != idx[p]);
            if (f) { ++cnt; myLast = p; }
        }
    }
    int before = blockExclScanMax(myLast, sdata);
    int lastStart0 = max(prevStart, before);

    int lastStart = lastStart0;
    int sumq = 0;
    for (int j = 0; j < EPT; ++j) {
        int p = base + j;
        if (p < n) {
            if ((p == 0) || (idx[p - 1] != idx[p])) lastStart = p;
            sumq += p - lastStart;
        }
    }

    int inclC = blockScanIncl(cnt, sdata);
    int inclQ = blockScanIncl(sumq, sdata);
    int ord  = segBase + inclC - cnt;
    int tcur = triBase + inclQ - sumq;

    lastStart = lastStart0;
    for (int j = 0; j < EPT; ++j) {
        int p = base + j;
        if (p < n) {
            bool f = (p == 0) || (idx[p - 1] != idx[p]);
            if (f) {
                segOff[ord] = p;
                triOff[ord] = tcur;
                ++ord;
                lastStart = p;
            }
            tcur += p - lastStart;
        }
    }
    if (bid == NB - 1 && tid == THREADS - 1) {
        int nseg = segBase + inclC;
        *nsegPtr = nseg;
        segOff[nseg] = n;                  // sentinel
    }
}

// ---------------------------------------------------------------------------
// Fill helpers.
// ---------------------------------------------------------------------------
// exact decode of backward rank rr for segment size c -> local (a,b), b>a
__device__ __forceinline__ void decodeRank(int rr, int c, int& a, int& b) {
    int k = (int)floorf((sqrtf((float)(8 * rr + 1)) - 1.0f) * 0.5f);
    if (k < 0) k = 0;
    while ((k + 1) * (k + 2) / 2 <= rr) ++k;   // exact fix-up
    while (k * (k + 1) / 2 > rr) --k;
    a = c - 2 - k;
    b = c - 1 - (rr - k * (k + 1) / 2);
}

__device__ __forceinline__ void emitOne(int r, int M, int c, int t0, int baseP,
                                        int s, int* __restrict__ outI,
                                        int* __restrict__ outJ,
                                        int* __restrict__ outK) {
    int a, b;
    decodeRank(M - 1 - r, c, a, b);
    int t = t0 + r;
    outI[t] = s;
    outJ[t] = baseP + a;
    outK[t] = baseP + b;
}

// store 4 consecutive ints at element offset t (t % 4 == 0) into stream P
// whose base has element phase PH (= stream_offset % 4) relative to 16B.
template <int PH>
__device__ __forceinline__ void storeQuad(int* __restrict__ P, int t, int4 v) {
    if constexpr (PH == 0) {
        *reinterpret_cast<int4*>(P + t) = v;
    } else if constexpr (PH == 2) {
        *reinterpret_cast<int2*>(P + t)     = make_int2(v.x, v.y);
        *reinterpret_cast<int2*>(P + t + 2) = make_int2(v.z, v.w);
    } else {
        P[t] = v.x;
        *reinterpret_cast<int2*>(P + t + 1) = make_int2(v.y, v.z);
        P[t + 3] = v.w;
    }
}

// ---------------------------------------------------------------------------
// Kernel C (hot): triple-balanced fill, QUAD inner loop (r9 structure,
// cached stores). Each lane decodes one rank exactly, derives the next 3 via
// the lexicographic successor rule, stores 16B per stream.
// ---------------------------------------------------------------------------
template <int TMOD4>
__global__ void k_fill(const int* __restrict__ segOff,
                       const int* __restrict__ triOff,
                       const int* __restrict__ nsegPtr, int T,
                       int* __restrict__ outI, int* __restrict__ outJ,
                       int* __restrict__ outK) {
    constexpr int PHJ = TMOD4 & 3;          // element phase of outJ = T % 4
    constexpr int PHK = (2 * TMOD4) & 3;    // element phase of outK = 2T % 4
    int nseg = *nsegPtr;
    int w = blockIdx.x * (THREADS / 64) + (threadIdx.x >> 6);
    int lane = threadIdx.x & 63;
    int nW = gridDim.x * (THREADS / 64);
    long long tlo = (long long)T * w / nW;
    long long thi = (long long)T * (w + 1) / nW;
    if (tlo >= thi) return;

    // largest s with triOff[s] <= tlo
    int lo = 0, hi = nseg - 1;
    while (lo < hi) {
        int mid = (lo + hi + 1) >> 1;
        if (triOff[mid] <= (int)tlo) lo = mid; else hi = mid - 1;
    }
    int s = lo;
    long long t = tlo;
    while (t < thi && s < nseg) {
        int baseP = segOff[s];
        int c = segOff[s + 1] - baseP;
        int M = c * (c - 1) / 2;
        int t0 = triOff[s];
        int rstart = (int)(t - t0);
        int rend = M;
        { long long cap = thi - t0; if (cap < (long long)rend) rend = (int)cap; }

        // quad grid anchored at absolute t % 4 == 0 (t = t0 + r)
        int rA = rstart + ((4 - ((t0 + rstart) & 3)) & 3);
        if (rA > rend) rA = rend;
        int rB = rA + ((rend - rA) & ~3);

        // head (<=3) and tail (<=3) scalars, lane-strided
        for (int r = rstart + lane; r < rA; r += 64)
            emitOne(r, M, c, t0, baseP, s, outI, outJ, outK);
        for (int r = rB + lane; r < rend; r += 64)
            emitOne(r, M, c, t0, baseP, s, outI, outJ, outK);

        // quad interior
        int nq = (rB - rA) >> 2;
        for (int q = lane; q < nq; q += 64) {
            int r = rA + 4 * q;
            int a0, b0;
            decodeRank(M - 1 - r, c, a0, b0);
            int a1 = (b0 == c - 1) ? a0 + 1 : a0;
            int b1 = (b0 == c - 1) ? a0 + 2 : b0 + 1;
            int a2 = (b1 == c - 1) ? a1 + 1 : a1;
            int b2 = (b1 == c - 1) ? a1 + 2 : b1 + 1;
            int a3 = (b2 == c - 1) ? a2 + 1 : a2;
            int b3 = (b2 == c - 1) ? a2 + 2 : b2 + 1;
            int tt = t0 + r;                      // tt % 4 == 0
            storeQuad<0>(outI, tt, make_int4(s, s, s, s));
            storeQuad<PHJ>(outJ, tt,
                make_int4(baseP + a0, baseP + a1, baseP + a2, baseP + a3));
            storeQuad<PHK>(outK, tt,
                make_int4(baseP + b0, baseP + b1, baseP + b2, baseP + b3));
        }
        t = (long long)t0 + rend;
        ++s;
    }
}

extern "C" void kernel_launch(void* const* d_in, const int* in_sizes, int n_in,
                              void* d_out, int out_size, void* d_ws, size_t ws_size,
                              hipStream_t stream) {
    const int* idx = (const int*)d_in[0];
    int n = in_sizes[0];
    int T = out_size / 3;
    int* out = (int*)d_out;
    int* ws = (int*)d_ws;

    // workspace layout (ints)
    int* nsegPtr     = ws;                       // [1]
    int* chunkCnt    = ws + 16;                  // [8192]
    int* chunkTriSum = ws + 16 + 8192;           // [8192]
    int* segOff      = ws + 16 + 16384;          // [n+1] (sentinel at nseg)
    int* triOff      = segOff + (n + 1);         // [n]

    int chunk = THREADS * EPT;                   // 2048
    int NB = (n + chunk - 1) / chunk;            // 782 for n=1.6M

    hipLaunchKernelGGL(k_chunkstats, dim3(NB), dim3(THREADS), 0, stream,
                       idx, n, chunkCnt, chunkTriSum);
    hipLaunchKernelGGL(k_emit, dim3(NB), dim3(THREADS), 0, stream,
                       idx, n, NB, chunkCnt, chunkTriSum,
                       segOff, triOff, nsegPtr);
    int* outI = out;
    int* outJ = out + T;
    int* outK = out + 2 * T;
    switch (T & 3) {
        case 0:
            hipLaunchKernelGGL((k_fill<0>), dim3(FILL_BLOCKS), dim3(THREADS), 0,
                               stream, segOff, triOff, nsegPtr, T, outI, outJ, outK);
            break;
        case 1:
            hipLaunchKernelGGL((k_fill<1>), dim3(FILL_BLOCKS), dim3(THREADS), 0,
                               stream, segOff, triOff, nsegPtr, T, outI, outJ, outK);
            break;
        case 2:
            hipLaunchKernelGGL((k_fill<2>), dim3(FILL_BLOCKS), dim3(THREADS), 0,
                               stream, segOff, triOff, nsegPtr, T, outI, outJ, outK);
            break;
        default:
            hipLaunchKernelGGL((k_fill<3>), dim3(FILL_BLOCKS), dim3(THREADS), 0,
                               stream, segOff, triOff, nsegPtr, T, outI, outJ, outK);
            break;
    }
}

// Round 14
// 83.840 us; speedup vs baseline: 1.5943x; 1.0282x over previous
//
#include <hip/hip_runtime.h>

#define THREADS 256                // prep kernels
#define EPT 8                      // elements per thread; chunk = 2048
#define FILL_THREADS 192           // 3 waves: one output stream each
#define FILL_BLOCKS 8192           // short per-wave ranges (~6 segments)

// ---------------------------------------------------------------------------
// Block helpers (each leaves sdata reusable: trailing __syncthreads()).
// ---------------------------------------------------------------------------
__device__ __forceinline__ int blockReduceSum(int v, int* sdata) {
    int tid = threadIdx.x;
    sdata[tid] = v;
    __syncthreads();
    for (int off = THREADS >> 1; off > 0; off >>= 1) {
        if (tid < off) sdata[tid] += sdata[tid + off];
        __syncthreads();
    }
    int r = sdata[0];
    __syncthreads();
    return r;
}

__device__ __forceinline__ int blockScanIncl(int v, int* sdata) {
    int tid = threadIdx.x;
    sdata[tid] = v;
    __syncthreads();
    for (int off = 1; off < THREADS; off <<= 1) {
        int t = 0;
        if (tid >= off) t = sdata[tid - off];
        __syncthreads();
        if (tid >= off) sdata[tid] += t;
        __syncthreads();
    }
    int r = sdata[tid];
    __syncthreads();
    return r;
}

// exclusive max-scan (identity -1): result for tid = max over threads < tid
__device__ __forceinline__ int blockExclScanMax(int v, int* sdata) {
    int tid = threadIdx.x;
    sdata[tid] = v;
    __syncthreads();
    for (int off = 1; off < THREADS; off <<= 1) {
        int t = -1;
        if (tid >= off) t = sdata[tid - off];
        __syncthreads();
        if (tid >= off) sdata[tid] = max(sdata[tid], t);
        __syncthreads();
    }
    int r = (tid == 0) ? -1 : sdata[tid - 1];
    __syncthreads();
    return r;
}

// ---------------------------------------------------------------------------
// Find the last segment-start position <= B0-1 (requires B0 > 0).
// ---------------------------------------------------------------------------
__device__ int findPrevStart(const int* __restrict__ idx, int B0,
                             int* sdata, int* s_found) {
    int tid = threadIdx.x;
    if (tid == 0) *s_found = -1;
    __syncthreads();
    int res = -1;
    for (int step = 0; res < 0; ++step) {
        int p = B0 - 1 - step * THREADS - tid;
        int cand = -1;
        if (p >= 0) {
            bool f = (p == 0) || (idx[p - 1] != idx[p]);
            if (f) cand = p;
        }
        sdata[tid] = cand;
        __syncthreads();
        for (int off = THREADS >> 1; off > 0; off >>= 1) {
            if (tid < off) sdata[tid] = max(sdata[tid], sdata[tid + off]);
            __syncthreads();
        }
        if (tid == 0 && sdata[0] >= 0) *s_found = sdata[0];
        __syncthreads();
        res = *s_found;
        __syncthreads();
    }
    return res;
}

// ---------------------------------------------------------------------------
// Kernel A: per-chunk (startCount, sum of local ranks q(p) = p - lastStart).
// ---------------------------------------------------------------------------
__global__ void k_chunkstats(const int* __restrict__ idx, int n,
                             int* __restrict__ chunkCnt,
                             int* __restrict__ chunkTriSum) {
    __shared__ int sdata[THREADS];
    __shared__ int s_tmp;
    int tid = threadIdx.x, bid = blockIdx.x;
    int B0 = bid * (THREADS * EPT);

    int prevStart = 0;
    if (bid > 0) prevStart = findPrevStart(idx, B0, sdata, &s_tmp);

    int base = B0 + tid * EPT;
    int cnt = 0, myLast = -1;
    for (int j = 0; j < EPT; ++j) {
        int p = base + j;
        if (p < n) {
            bool f = (p == 0) || (idx[p - 1] != idx[p]);
            if (f) { ++cnt; myLast = p; }
        }
    }
    int before = blockExclScanMax(myLast, sdata);
    int lastStart = max(prevStart, before);
    int sumq = 0;
    for (int j = 0; j < EPT; ++j) {
        int p = base + j;
        if (p < n) {
            if ((p == 0) || (idx[p - 1] != idx[p])) lastStart = p;
            sumq += p - lastStart;
        }
    }
    int c = blockReduceSum(cnt, sdata);
    int q = blockReduceSum(sumq, sdata);
    if (tid == 0) { chunkCnt[bid] = c; chunkTriSum[bid] = q; }
}

// ---------------------------------------------------------------------------
// Kernel B: chunk-level redundant prefix, emit segOff + triOff + nseg.
// ---------------------------------------------------------------------------
__global__ void k_emit(const int* __restrict__ idx, int n, int NB,
                       const int* __restrict__ chunkCnt,
                       const int* __restrict__ chunkTriSum,
                       int* __restrict__ segOff, int* __restrict__ triOff,
                       int* __restrict__ nsegPtr) {
    __shared__ int sdata[THREADS];
    __shared__ int s_tmp;
    int tid = threadIdx.x, bid = blockIdx.x;
    int B0 = bid * (THREADS * EPT);

    int prevStart = 0;
    if (bid > 0) prevStart = findPrevStart(idx, B0, sdata, &s_tmp);

    int pv = 0, tv = 0;
    for (int i = tid; i < bid; i += THREADS) {
        pv += chunkCnt[i];
        tv += chunkTriSum[i];
    }
    int segBase = blockReduceSum(pv, sdata);
    int triBase = blockReduceSum(tv, sdata);

    int base = B0 + tid * EPT;
    int cnt = 0, myLast = -1;
    for (int j = 0; j < EPT; ++j) {
        int p = base + j;
        if (p < n) {
            bool f = (p == 0) || (idx[p - 1] != idx[p]);
            if (f) { ++cnt; myLast = p; }
        }
    }
    int before = blockExclScanMax(myLast, sdata);
    int lastStart0 = max(prevStart, before);

    int lastStart = lastStart0;
    int sumq = 0;
    for (int j = 0; j < EPT; ++j) {
        int p = base + j;
        if (p < n) {
            if ((p == 0) || (idx[p - 1] != idx[p])) lastStart = p;
            sumq += p - lastStart;
        }
    }

    int inclC = blockScanIncl(cnt, sdata);
    int inclQ = blockScanIncl(sumq, sdata);
    int ord  = segBase + inclC - cnt;
    int tcur = triBase + inclQ - sumq;

    lastStart = lastStart0;
    for (int j = 0; j < EPT; ++j) {
        int p = base + j;
        if (p < n) {
            bool f = (p == 0) || (idx[p - 1] != idx[p]);
            if (f) {
                segOff[ord] = p;
                triOff[ord] = tcur;
                ++ord;
                lastStart = p;
            }
            tcur += p - lastStart;
        }
    }
    if (bid == NB - 1 && tid == THREADS - 1) {
        int nseg = segBase + inclC;
        *nsegPtr = nseg;
        segOff[nseg] = n;                  // sentinel
    }
}

// ---------------------------------------------------------------------------
// Fill helpers.
// ---------------------------------------------------------------------------
// exact decode of backward rank rr for segment size c -> local (a,b), b>a
__device__ __forceinline__ void decodeRank(int rr, int c, int& a, int& b) {
    int k = (int)floorf((sqrtf((float)(8 * rr + 1)) - 1.0f) * 0.5f);
    if (k < 0) k = 0;
    while ((k + 1) * (k + 2) / 2 <= rr) ++k;   // exact fix-up
    while (k * (k + 1) / 2 > rr) --k;
    a = c - 2 - k;
    b = c - 1 - (rr - k * (k + 1) / 2);
}

// value of output stream PASS (0:I=s, 1:J=baseP+a, 2:K=baseP+b) at rank r
template <int PASS>
__device__ __forceinline__ int rankValue(int r, int M, int c, int baseP, int s) {
    if constexpr (PASS == 0) { (void)M; (void)c; (void)baseP; return s; }
    int a, b;
    decodeRank(M - 1 - r, c, a, b);
    return (PASS == 1) ? baseP + a : baseP + b;
}

// store 4 consecutive ints at element offset t (t % 4 == 0) into stream P
// whose base has element phase PH (= stream_offset % 4) relative to 16B.
template <int PH>
__device__ __forceinline__ void storeQuad(int* __restrict__ P, int t, int4 v) {
    if constexpr (PH == 0) {
        *reinterpret_cast<int4*>(P + t) = v;
    } else if constexpr (PH == 2) {
        *reinterpret_cast<int2*>(P + t)     = make_int2(v.x, v.y);
        *reinterpret_cast<int2*>(P + t + 2) = make_int2(v.z, v.w);
    } else {
        P[t] = v.x;
        *reinterpret_cast<int2*>(P + t + 1) = make_int2(v.y, v.z);
        P[t + 3] = v.w;
    }
}

// ---------------------------------------------------------------------------
// One wave fills ONE stream over triple-rows [tlo, thi): binary search, then
// walk segments; quad stores, lexicographic successor for ranks +1..+3.
// (Validated in r10; cached stores.)
// ---------------------------------------------------------------------------
template <int PASS, int PH>
__device__ void fillStream(const int* __restrict__ segOff,
                           const int* __restrict__ triOff,
                           int nseg, long long tlo, long long thi, int lane,
                           int* __restrict__ P) {
    int lo = 0, hi = nseg - 1;
    while (lo < hi) {
        int mid = (lo + hi + 1) >> 1;
        if (triOff[mid] <= (int)tlo) lo = mid; else hi = mid - 1;
    }
    int s = lo;
    long long t = tlo;
    while (t < thi && s < nseg) {
        int baseP = segOff[s];
        int c = segOff[s + 1] - baseP;
        int M = c * (c - 1) / 2;
        int t0 = triOff[s];
        int rstart = (int)(t - t0);
        int rend = M;
        { long long cap = thi - t0; if (cap < (long long)rend) rend = (int)cap; }

        int rA = rstart + ((4 - ((t0 + rstart) & 3)) & 3);
        if (rA > rend) rA = rend;
        int rB = rA + ((rend - rA) & ~3);

        for (int r = rstart + lane; r < rA; r += 64)
            P[t0 + r] = rankValue<PASS>(r, M, c, baseP, s);
        for (int r = rB + lane; r < rend; r += 64)
            P[t0 + r] = rankValue<PASS>(r, M, c, baseP, s);

        int nq = (rB - rA) >> 2;
        for (int q = lane; q < nq; q += 64) {
            int r = rA + 4 * q;
            int4 v;
            if constexpr (PASS == 0) {
                v = make_int4(s, s, s, s);
            } else {
                int a0, b0;
                decodeRank(M - 1 - r, c, a0, b0);
                int a1 = (b0 == c - 1) ? a0 + 1 : a0;
                int b1 = (b0 == c - 1) ? a0 + 2 : b0 + 1;
                int a2 = (b1 == c - 1) ? a1 + 1 : a1;
                int b2 = (b1 == c - 1) ? a1 + 2 : b1 + 1;
                int a3 = (b2 == c - 1) ? a2 + 1 : a2;
                int b3 = (b2 == c - 1) ? a2 + 2 : b2 + 1;
                v = (PASS == 1)
                    ? make_int4(baseP + a0, baseP + a1, baseP + a2, baseP + a3)
                    : make_int4(baseP + b0, baseP + b1, baseP + b2, baseP + b3);
            }
            storeQuad<PH>(P, t0 + r, v);
        }
        t = (long long)t0 + rend;
        ++s;
    }
}

// ---------------------------------------------------------------------------
// Kernel C (hot): 192-thread blocks = 3 waves. Block b owns triple range
// [T*b/NBF, T*(b+1)/NBF); wave 0 -> outI, wave 1 -> outJ, wave 2 -> outK.
// Each wave: one short sequential store run (~12.5 KB), walk ~6 segments.
// Isolates stream-per-wave from walk-length (r10's confound).
// ---------------------------------------------------------------------------
template <int TMOD4>
__global__ void k_fill(const int* __restrict__ segOff,
                       const int* __restrict__ triOff,
                       const int* __restrict__ nsegPtr, int T,
                       int* __restrict__ outI, int* __restrict__ outJ,
                       int* __restrict__ outK) {
    constexpr int PHJ = TMOD4 & 3;          // element phase of outJ = T % 4
    constexpr int PHK = (2 * TMOD4) & 3;    // element phase of outK = 2T % 4
    int nseg = *nsegPtr;
    int pass = threadIdx.x >> 6;            // 0,1,2 — wave-uniform
    int lane = threadIdx.x & 63;
    int b = blockIdx.x;
    int NBF = gridDim.x;
    long long tlo = (long long)T * b / NBF;
    long long thi = (long long)T * (b + 1) / NBF;
    if (tlo >= thi) return;

    if (pass == 0)
        fillStream<0, 0>(segOff, triOff, nseg, tlo, thi, lane, outI);
    else if (pass == 1)
        fillStream<1, PHJ>(segOff, triOff, nseg, tlo, thi, lane, outJ);
    else
        fillStream<2, PHK>(segOff, triOff, nseg, tlo, thi, lane, outK);
}

extern "C" void kernel_launch(void* const* d_in, const int* in_sizes, int n_in,
                              void* d_out, int out_size, void* d_ws, size_t ws_size,
                              hipStream_t stream) {
    const int* idx = (const int*)d_in[0];
    int n = in_sizes[0];
    int T = out_size / 3;
    int* out = (int*)d_out;
    int* ws = (int*)d_ws;

    // workspace layout (ints)
    int* nsegPtr     = ws;                       // [1]
    int* chunkCnt    = ws + 16;                  // [8192]
    int* chunkTriSum = ws + 16 + 8192;           // [8192]
    int* segOff      = ws + 16 + 16384;          // [n+1] (sentinel at nseg)
    int* triOff      = segOff + (n + 1);         // [n]

    int chunk = THREADS * EPT;                   // 2048
    int NB = (n + chunk - 1) / chunk;            // 782 for n=1.6M

    hipLaunchKernelGGL(k_chunkstats, dim3(NB), dim3(THREADS), 0, stream,
                       idx, n, chunkCnt, chunkTriSum);
    hipLaunchKernelGGL(k_emit, dim3(NB), dim3(THREADS), 0, stream,
                       idx, n, NB, chunkCnt, chunkTriSum,
                       segOff, triOff, nsegPtr);
    int* outI = out;
    int* outJ = out + T;
    int* outK = out + 2 * T;
    switch (T & 3) {
        case 0:
            hipLaunchKernelGGL((k_fill<0>), dim3(FILL_BLOCKS), dim3(FILL_THREADS), 0,
                               stream, segOff, triOff, nsegPtr, T, outI, outJ, outK);
            break;
        case 1:
            hipLaunchKernelGGL((k_fill<1>), dim3(FILL_BLOCKS), dim3(FILL_THREADS), 0,
                               stream, segOff, triOff, nsegPtr, T, outI, outJ, outK);
            break;
        case 2:
            hipLaunchKernelGGL((k_fill<2>), dim3(FILL_BLOCKS), dim3(FILL_THREADS), 0,
                               stream, segOff, triOff, nsegPtr, T, outI, outJ, outK);
            break;
        default:
            hipLaunchKernelGGL((k_fill<3>), dim3(FILL_BLOCKS), dim3(FILL_THREADS), 0,
                               stream, segOff, triOff, nsegPtr, T, outI, outJ, outK);
            break;
    }
}

// Round 15
// 83.457 us; speedup vs baseline: 1.6016x; 1.0046x over previous
//
#include <hip/hip_runtime.h>

#define THREADS 256
#define EPT 8                      // elements per thread; chunk = 2048
#define FILL_BLOCKS 4096

// ---------------------------------------------------------------------------
// Block helpers (each leaves sdata reusable: trailing __syncthreads()).
// ---------------------------------------------------------------------------
__device__ __forceinline__ int blockReduceSum(int v, int* sdata) {
    int tid = threadIdx.x;
    sdata[tid] = v;
    __syncthreads();
    for (int off = THREADS >> 1; off > 0; off >>= 1) {
        if (tid < off) sdata[tid] += sdata[tid + off];
        __syncthreads();
    }
    int r = sdata[0];
    __syncthreads();
    return r;
}

__device__ __forceinline__ int blockScanIncl(int v, int* sdata) {
    int tid = threadIdx.x;
    sdata[tid] = v;
    __syncthreads();
    for (int off = 1; off < THREADS; off <<= 1) {
        int t = 0;
        if (tid >= off) t = sdata[tid - off];
        __syncthreads();
        if (tid >= off) sdata[tid] += t;
        __syncthreads();
    }
    int r = sdata[tid];
    __syncthreads();
    return r;
}

// exclusive max-scan (identity -1): result for tid = max over threads < tid
__device__ __forceinline__ int blockExclScanMax(int v, int* sdata) {
    int tid = threadIdx.x;
    sdata[tid] = v;
    __syncthreads();
    for (int off = 1; off < THREADS; off <<= 1) {
        int t = -1;
        if (tid >= off) t = sdata[tid - off];
        __syncthreads();
        if (tid >= off) sdata[tid] = max(sdata[tid], t);
        __syncthreads();
    }
    int r = (tid == 0) ? -1 : sdata[tid - 1];
    __syncthreads();
    return r;
}

// ---------------------------------------------------------------------------
// Find the last segment-start position <= B0-1 (requires B0 > 0).
// ---------------------------------------------------------------------------
__device__ int findPrevStart(const int* __restrict__ idx, int B0,
                             int* sdata, int* s_found) {
    int tid = threadIdx.x;
    if (tid == 0) *s_found = -1;
    __syncthreads();
    int res = -1;
    for (int step = 0; res < 0; ++step) {
        int p = B0 - 1 - step * THREADS - tid;
        int cand = -1;
        if (p >= 0) {
            bool f = (p == 0) || (idx[p - 1] != idx[p]);
            if (f) cand = p;
        }
        sdata[tid] = cand;
        __syncthreads();
        for (int off = THREADS >> 1; off > 0; off >>= 1) {
            if (tid < off) sdata[tid] = max(sdata[tid], sdata[tid + off]);
            __syncthreads();
        }
        if (tid == 0 && sdata[0] >= 0) *s_found = sdata[0];
        __syncthreads();
        res = *s_found;
        __syncthreads();
    }
    return res;
}

// ---------------------------------------------------------------------------
// Kernel A: per-chunk (startCount, sum of local ranks q(p) = p - lastStart).
// ---------------------------------------------------------------------------
__global__ void k_chunkstats(const int* __restrict__ idx, int n,
                             int* __restrict__ chunkCnt,
                             int* __restrict__ chunkTriSum) {
    __shared__ int sdata[THREADS];
    __shared__ int s_tmp;
    int tid = threadIdx.x, bid = blockIdx.x;
    int B0 = bid * (THREADS * EPT);

    int prevStart = 0;
    if (bid > 0) prevStart = findPrevStart(idx, B0, sdata, &s_tmp);

    int base = B0 + tid * EPT;
    int cnt = 0, myLast = -1;
    for (int j = 0; j < EPT; ++j) {
        int p = base + j;
        if (p < n) {
            bool f = (p == 0) || (idx[p - 1] != idx[p]);
            if (f) { ++cnt; myLast = p; }
        }
    }
    int before = blockExclScanMax(myLast, sdata);
    int lastStart = max(prevStart, before);
    int sumq = 0;
    for (int j = 0; j < EPT; ++j) {
        int p = base + j;
        if (p < n) {
            if ((p == 0) || (idx[p - 1] != idx[p])) lastStart = p;
            sumq += p - lastStart;
        }
    }
    int c = blockReduceSum(cnt, sdata);
    int q = blockReduceSum(sumq, sdata);
    if (tid == 0) { chunkCnt[bid] = c; chunkTriSum[bid] = q; }
}

// ---------------------------------------------------------------------------
// Kernel B: chunk-level redundant prefix, emit segOff + triOff + nseg.
// ---------------------------------------------------------------------------
__global__ void k_emit(const int* __restrict__ idx, int n, int NB,
                       const int* __restrict__ chunkCnt,
                       const int* __restrict__ chunkTriSum,
                       int* __restrict__ segOff, int* __restrict__ triOff,
                       int* __restrict__ nsegPtr) {
    __shared__ int sdata[THREADS];
    __shared__ int s_tmp;
    int tid = threadIdx.x, bid = blockIdx.x;
    int B0 = bid * (THREADS * EPT);

    int prevStart = 0;
    if (bid > 0) prevStart = findPrevStart(idx, B0, sdata, &s_tmp);

    int pv = 0, tv = 0;
    for (int i = tid; i < bid; i += THREADS) {
        pv += chunkCnt[i];
        tv += chunkTriSum[i];
    }
    int segBase = blockReduceSum(pv, sdata);
    int triBase = blockReduceSum(tv, sdata);

    int base = B0 + tid * EPT;
    int cnt = 0, myLast = -1;
    for (int j = 0; j < EPT; ++j) {
        int p = base + j;
        if (p < n) {
            bool f = (p == 0) || (idx[p - 1] != idx[p]);
            if (f) { ++cnt; myLast = p; }
        }
    }
    int before = blockExclScanMax(myLast, sdata);
    int lastStart0 = max(prevStart, before);

    int lastStart = lastStart0;
    int sumq = 0;
    for (int j = 0; j < EPT; ++j) {
        int p = base + j;
        if (p < n) {
            if ((p == 0) || (idx[p - 1] != idx[p])) lastStart = p;
            sumq += p - lastStart;
        }
    }

    int inclC = blockScanIncl(cnt, sdata);
    int inclQ = blockScanIncl(sumq, sdata);
    int ord  = segBase + inclC - cnt;
    int tcur = triBase + inclQ - sumq;

    lastStart = lastStart0;
    for (int j = 0; j < EPT; ++j) {
        int p = base + j;
        if (p < n) {
            bool f = (p == 0) || (idx[p - 1] != idx[p]);
            if (f) {
                segOff[ord] = p;
                triOff[ord] = tcur;
                ++ord;
                lastStart = p;
            }
            tcur += p - lastStart;
        }
    }
    if (bid == NB - 1 && tid == THREADS - 1) {
        int nseg = segBase + inclC;
        *nsegPtr = nseg;
        segOff[nseg] = n;                  // sentinel
    }
}

// ---------------------------------------------------------------------------
// Fill helpers.
// ---------------------------------------------------------------------------
// exact decode of backward rank rr for segment size c -> local (a,b), b>a
__device__ __forceinline__ void decodeRank(int rr, int c, int& a, int& b) {
    int k = (int)floorf((sqrtf((float)(8 * rr + 1)) - 1.0f) * 0.5f);
    if (k < 0) k = 0;
    while ((k + 1) * (k + 2) / 2 <= rr) ++k;   // exact fix-up
    while (k * (k + 1) / 2 > rr) --k;
    a = c - 2 - k;
    b = c - 1 - (rr - k * (k + 1) / 2);
}

__device__ __forceinline__ void emitOne(int r, int M, int c, int t0, int baseP,
                                        int s, int* __restrict__ outI,
                                        int* __restrict__ outJ,
                                        int* __restrict__ outK) {
    int a, b;
    decodeRank(M - 1 - r, c, a, b);
    int t = t0 + r;
    outI[t] = s;
    outJ[t] = baseP + a;
    outK[t] = baseP + b;
}

// store 4 consecutive ints at element offset t (t % 4 == 0) into stream P
// whose base has element phase PH (= stream_offset % 4) relative to 16B.
template <int PH>
__device__ __forceinline__ void storeQuad(int* __restrict__ P, int t, int4 v) {
    if constexpr (PH == 0) {
        *reinterpret_cast<int4*>(P + t) = v;
    } else if constexpr (PH == 2) {
        *reinterpret_cast<int2*>(P + t)     = make_int2(v.x, v.y);
        *reinterpret_cast<int2*>(P + t + 2) = make_int2(v.z, v.w);
    } else {
        P[t] = v.x;
        *reinterpret_cast<int2*>(P + t + 1) = make_int2(v.y, v.z);
        P[t + 3] = v.w;
    }
}

// ---------------------------------------------------------------------------
// Kernel C (hot): triple-balanced fill, QUAD inner loop. Each lane decodes
// one rank exactly, derives the next 3 via the lexicographic successor rule
// (b==c-1 ? (a+1,a+2) : (a,b+1)), stores 16B per stream (phase-templated).
// Best-measured variant (r9, 81.2 us).
// ---------------------------------------------------------------------------
template <int TMOD4>
__global__ void k_fill(const int* __restrict__ segOff,
                       const int* __restrict__ triOff,
                       const int* __restrict__ nsegPtr, int T,
                       int* __restrict__ outI, int* __restrict__ outJ,
                       int* __restrict__ outK) {
    constexpr int PHJ = TMOD4 & 3;          // element phase of outJ = T % 4
    constexpr int PHK = (2 * TMOD4) & 3;    // element phase of outK = 2T % 4
    int nseg = *nsegPtr;
    int w = blockIdx.x * (THREADS / 64) + (threadIdx.x >> 6);
    int lane = threadIdx.x & 63;
    int nW = gridDim.x * (THREADS / 64);
    long long tlo = (long long)T * w / nW;
    long long thi = (long long)T * (w + 1) / nW;
    if (tlo >= thi) return;

    // largest s with triOff[s] <= tlo
    int lo = 0, hi = nseg - 1;
    while (lo < hi) {
        int mid = (lo + hi + 1) >> 1;
        if (triOff[mid] <= (int)tlo) lo = mid; else hi = mid - 1;
    }
    int s = lo;
    long long t = tlo;
    while (t < thi && s < nseg) {
        int baseP = segOff[s];
        int c = segOff[s + 1] - baseP;
        int M = c * (c - 1) / 2;
        int t0 = triOff[s];
        int rstart = (int)(t - t0);
        int rend = M;
        { long long cap = thi - t0; if (cap < (long long)rend) rend = (int)cap; }

        // quad grid anchored at absolute t % 4 == 0 (t = t0 + r)
        int rA = rstart + ((4 - ((t0 + rstart) & 3)) & 3);
        if (rA > rend) rA = rend;
        int rB = rA + ((rend - rA) & ~3);

        // head (<=3) and tail (<=3) scalars, lane-strided
        for (int r = rstart + lane; r < rA; r += 64)
            emitOne(r, M, c, t0, baseP, s, outI, outJ, outK);
        for (int r = rB + lane; r < rend; r += 64)
            emitOne(r, M, c, t0, baseP, s, outI, outJ, outK);

        // quad interior
        int nq = (rB - rA) >> 2;
        for (int q = lane; q < nq; q += 64) {
            int r = rA + 4 * q;
            int a0, b0;
            decodeRank(M - 1 - r, c, a0, b0);
            int a1 = (b0 == c - 1) ? a0 + 1 : a0;
            int b1 = (b0 == c - 1) ? a0 + 2 : b0 + 1;
            int a2 = (b1 == c - 1) ? a1 + 1 : a1;
            int b2 = (b1 == c - 1) ? a1 + 2 : b1 + 1;
            int a3 = (b2 == c - 1) ? a2 + 1 : a2;
            int b3 = (b2 == c - 1) ? a2 + 2 : b2 + 1;
            int tt = t0 + r;                      // tt % 4 == 0
            storeQuad<0>(outI, tt, make_int4(s, s, s, s));
            storeQuad<PHJ>(outJ, tt,
                make_int4(baseP + a0, baseP + a1, baseP + a2, baseP + a3));
            storeQuad<PHK>(outK, tt,
                make_int4(baseP + b0, baseP + b1, baseP + b2, baseP + b3));
        }
        t = (long long)t0 + rend;
        ++s;
    }
}

extern "C" void kernel_launch(void* const* d_in, const int* in_sizes, int n_in,
                              void* d_out, int out_size, void* d_ws, size_t ws_size,
                              hipStream_t stream) {
    const int* idx = (const int*)d_in[0];
    int n = in_sizes[0];
    int T = out_size / 3;
    int* out = (int*)d_out;
    int* ws = (int*)d_ws;

    // workspace layout (ints)
    int* nsegPtr     = ws;                       // [1]
    int* chunkCnt    = ws + 16;                  // [8192]
    int* chunkTriSum = ws + 16 + 8192;           // [8192]
    int* segOff      = ws + 16 + 16384;          // [n+1] (sentinel at nseg)
    int* triOff      = segOff + (n + 1);         // [n]

    int chunk = THREADS * EPT;                   // 2048
    int NB = (n + chunk - 1) / chunk;            // 782 for n=1.6M

    hipLaunchKernelGGL(k_chunkstats, dim3(NB), dim3(THREADS), 0, stream,
                       idx, n, chunkCnt, chunkTriSum);
    hipLaunchKernelGGL(k_emit, dim3(NB), dim3(THREADS), 0, stream,
                       idx, n, NB, chunkCnt, chunkTriSum,
                       segOff, triOff, nsegPtr);
    int* outI = out;
    int* outJ = out + T;
    int* outK = out + 2 * T;
    switch (T & 3) {
        case 0:
            hipLaunchKernelGGL((k_fill<0>), dim3(FILL_BLOCKS), dim3(THREADS), 0,
                               stream, segOff, triOff, nsegPtr, T, outI, outJ, outK);
            break;
        case 1:
            hipLaunchKernelGGL((k_fill<1>), dim3(FILL_BLOCKS), dim3(THREADS), 0,
                               stream, segOff, triOff, nsegPtr, T, outI, outJ, outK);
            break;
        case 2:
            hipLaunchKernelGGL((k_fill<2>), dim3(FILL_BLOCKS), dim3(THREADS), 0,
                               stream, segOff, triOff, nsegPtr, T, outI, outJ, outK);
            break;
        default:
            hipLaunchKernelGGL((k_fill<3>), dim3(FILL_BLOCKS), dim3(THREADS), 0,
                               stream, segOff, triOff, nsegPtr, T, outI, outJ, outK);
            break;
    }
}